// Round 8
// baseline (1993.576 us; speedup 1.0000x reference)
//
#include <hip/hip_runtime.h>
#include <stdint.h>

// SharedLSTM: B=64, S=512, D=512.
//  out = concat(hidden_seq [64,512,512], h_T [64,512], c_T [64,512]) fp32.
//
// Round 8 = round 7 with the stamped-h store offsets fixed: global_store
// offset imm is 13-bit SIGNED (max +4095); batch stride is 2048B so rows
// 2 and 3 need a second base register (hp + 4096B) instead of offset:4096/6144.
//
//  (a) 8 wgs/group (32 wgs): wave owns 16 d-cols x ALL 4 gates
//      (vfrag[4][16], 256 VGPR). MFMA C layout (col=lane&15=d,
//      row=(lane>>4)*4+reg=batch) puts i,f,g,o for one (batch,d) in the
//      SAME lane -> elementwise fully in-register, c-state f32[4]/lane.
//      Barrier B + gbuf deleted; one barrier per step. Poll fabric
//      redundancy halves (8 readers/tile instead of 16).
//  (b) 2-set pipelined poll: two 8-load sets round-robin; in-order vmcnt
//      retirement alternates them; detect quantization ~RT/2 -> ~100-300cy.
//  (c) x_proj exchanged via transposed padded LDS tile under barrier A
//      (double-buffered), read as ushort4 (4 batches) per gate.
//
// ws layout:
//   [262144, +134217728)  x_proj bf16 [32768][2048]
//   then Xcat (67MB) — head reused after k_gemm as stamped-h sh (256KB,
//        memset between k_gemm and k_lstm), WUt (4MB), Vt (2MB)

typedef __attribute__((ext_vector_type(8))) short short8;
typedef __attribute__((ext_vector_type(4))) float f32x4;
typedef __attribute__((ext_vector_type(2))) float f32x2;
typedef __attribute__((ext_vector_type(4))) unsigned int u32x4v;
typedef __attribute__((ext_vector_type(2))) unsigned int u32x2v;
typedef __attribute__((ext_vector_type(4))) unsigned short ushort4v;

__device__ __forceinline__ unsigned short f2bf(float x) {
  union { float f; unsigned v; } c; c.f = x;
  unsigned r = (c.v + 0x7fffu + ((c.v >> 16) & 1u)) >> 16;  // RNE
  return (unsigned short)r;
}
__device__ __forceinline__ float bf2f(unsigned short u) {
  union { unsigned v; float f; } c; c.v = (unsigned)u << 16; return c.f;
}
__device__ __forceinline__ float sigm(float x) { return 1.f / (1.f + __expf(-x)); }
__device__ __forceinline__ float tanh_f(float x) { return 1.f - 2.f / (__expf(2.f * x) + 1.f); }

// ---------------- 1) concat + fp32->bf16 ----------------
__global__ __launch_bounds__(256) void k_convX(const float* __restrict__ cas,
                                               const float* __restrict__ soc,
                                               unsigned short* __restrict__ Xcat) {
  size_t i = ((size_t)blockIdx.x * 256 + threadIdx.x) * 8;  // elem in 32768*1024
  int r = (int)(i >> 10), k0 = (int)(i & 1023);
  const float* src = (k0 < 512) ? cas + (size_t)r * 512 + k0
                                : soc + (size_t)r * 512 + (k0 - 512);
  f32x4 a = *(const f32x4*)src;
  f32x4 b = *(const f32x4*)(src + 4);
  short8 o;
  o[0] = (short)f2bf(a[0]); o[1] = (short)f2bf(a[1]);
  o[2] = (short)f2bf(a[2]); o[3] = (short)f2bf(a[3]);
  o[4] = (short)f2bf(b[0]); o[5] = (short)f2bf(b[1]);
  o[6] = (short)f2bf(b[2]); o[7] = (short)f2bf(b[3]);
  *(short8*)(Xcat + i) = o;
}

// ---------------- 2) transpose + convert: Out[n][kk] = src(kk,n) -----------
__global__ __launch_bounds__(256) void k_transpose(const float* __restrict__ S0,
                                                   const float* __restrict__ S1,
                                                   int split, int Ktot,
                                                   unsigned short* __restrict__ Out) {
  __shared__ float tile[64][65];
  int tk = blockIdx.x, tn = blockIdx.y, tid = threadIdx.x;
#pragma unroll
  for (int i = 0; i < 16; ++i) {
    int idx = i * 256 + tid;
    int kr = idx >> 6, nc = idx & 63;
    int kk = tk * 64 + kr;
    const float* s = (kk < split) ? S0 + (size_t)kk * 2048 + tn * 64 + nc
                                  : S1 + (size_t)(kk - split) * 2048 + tn * 64 + nc;
    tile[kr][nc] = *s;
  }
  __syncthreads();
#pragma unroll
  for (int i = 0; i < 16; ++i) {
    int idx = i * 256 + tid;
    int nr = idx >> 6, kc = idx & 63;
    Out[(size_t)(tn * 64 + nr) * Ktot + tk * 64 + kc] = f2bf(tile[kc][nr]);
  }
}

// ---------------- 3) x_proj GEMM: 128x128 tile, BK=32, global_load_lds ------
__global__ __launch_bounds__(256) void k_gemm(const unsigned short* __restrict__ A,
                                              const unsigned short* __restrict__ Bt,
                                              const float* __restrict__ bias,
                                              unsigned short* __restrict__ xproj) {
  __shared__ __attribute__((aligned(16))) unsigned short At[128 * 32];
  __shared__ __attribute__((aligned(16))) unsigned short Bs[128 * 32];
  int tn0 = blockIdx.x * 128, tm0 = blockIdx.y * 128;
  int tid = threadIdx.x, wave = tid >> 6, lane = tid & 63;
  int wr = wave >> 1, wc = wave & 1;
  f32x4 acc[4][4] = {};

  for (int kt = 0; kt < 32; ++kt) {
    __syncthreads();
#pragma unroll
    for (int i = 0; i < 2; ++i) {
      int cb = i * 256 + wave * 64;
      int c = cb + lane;
      const unsigned short* ga = A + (size_t)(tm0 + (c >> 2)) * 1024 + kt * 32 + (c & 3) * 8;
      __builtin_amdgcn_global_load_lds((const __attribute__((address_space(1))) void*)ga,
                                       (__attribute__((address_space(3))) void*)(At + cb * 8),
                                       16, 0, 0);
      const unsigned short* gb = Bt + (size_t)(tn0 + (c >> 2)) * 1024 + kt * 32 + (c & 3) * 8;
      __builtin_amdgcn_global_load_lds((const __attribute__((address_space(1))) void*)gb,
                                       (__attribute__((address_space(3))) void*)(Bs + cb * 8),
                                       16, 0, 0);
    }
    __syncthreads();
    short8 af[4], bf[4];
#pragma unroll
    for (int m = 0; m < 4; ++m)
      af[m] = *(const short8*)(At + (wr * 64 + m * 16 + (lane & 15)) * 32 + (lane >> 4) * 8);
#pragma unroll
    for (int n = 0; n < 4; ++n)
      bf[n] = *(const short8*)(Bs + (wc * 64 + n * 16 + (lane & 15)) * 32 + (lane >> 4) * 8);
#pragma unroll
    for (int m = 0; m < 4; ++m)
#pragma unroll
      for (int n = 0; n < 4; ++n)
        acc[m][n] = __builtin_amdgcn_mfma_f32_16x16x32_bf16(af[m], bf[n], acc[m][n], 0, 0, 0);
  }

#pragma unroll
  for (int n = 0; n < 4; ++n) {
    int cg = tn0 + wc * 64 + n * 16 + (lane & 15);
    float bv = bias[cg];
#pragma unroll
    for (int m = 0; m < 4; ++m) {
#pragma unroll
      for (int rr = 0; rr < 4; ++rr) {
        int rg = tm0 + wr * 64 + m * 16 + ((lane >> 4) << 2) + rr;  // r = b*512+s
        int orow = ((rg & 511) << 6) | (rg >> 9);                   // s*64+b
        xproj[(size_t)orow * 2048 + cg] = f2bf(acc[m][n][rr] + bv);
      }
    }
  }
}

// ---------------- 4) persistent recurrence, epoch-stamped ----------------
// wg = (bg = blockIdx>>3, dgp = blockIdx&7). Group = 8 wgs sharing bg
// (16 batches). wg owns d-cols [dgp*64, +64); wave owns 16 d-cols x 4 gates
// (vfrag[4][16]). sh dwords: sh[slot][batch][d] = (bf16 h) | (epoch<<16).
// Wave w polls the LINEAR slab rows [bg*16+4w, +4) x 512 d (8KB) with a
// 2-set pipelined poll, stages into LDS; one barrier; MFMA; in-register
// elementwise (lane owns 4 batches x 1 d-col for all 4 gates).

#define POLL_ISSUE(s0, s1, s2, s3, s4, s5, s6, s7)                        \
  asm volatile(                                                           \
      "global_load_dwordx4 %0, %8, off sc0 sc1\n\t"                       \
      "global_load_dwordx4 %1, %8, off offset:1024 sc0 sc1\n\t"           \
      "global_load_dwordx4 %2, %8, off offset:2048 sc0 sc1\n\t"           \
      "global_load_dwordx4 %3, %8, off offset:3072 sc0 sc1\n\t"           \
      "global_load_dwordx4 %4, %9, off sc0 sc1\n\t"                       \
      "global_load_dwordx4 %5, %9, off offset:1024 sc0 sc1\n\t"           \
      "global_load_dwordx4 %6, %9, off offset:2048 sc0 sc1\n\t"           \
      "global_load_dwordx4 %7, %9, off offset:3072 sc0 sc1"               \
      : "=&v"(s0), "=&v"(s1), "=&v"(s2), "=&v"(s3), "=&v"(s4), "=&v"(s5), \
        "=&v"(s6), "=&v"(s7)                                              \
      : "v"(pb), "v"(pb4)                                                 \
      : "memory")

#define POLL_CHECK(s0, s1, s2, s3, s4, s5, s6, s7)                          \
  ((s0[0] ^ tsh) | (s0[1] ^ tsh) | (s0[2] ^ tsh) | (s0[3] ^ tsh) |          \
   (s1[0] ^ tsh) | (s1[1] ^ tsh) | (s1[2] ^ tsh) | (s1[3] ^ tsh) |          \
   (s2[0] ^ tsh) | (s2[1] ^ tsh) | (s2[2] ^ tsh) | (s2[3] ^ tsh) |          \
   (s3[0] ^ tsh) | (s3[1] ^ tsh) | (s3[2] ^ tsh) | (s3[3] ^ tsh) |          \
   (s4[0] ^ tsh) | (s4[1] ^ tsh) | (s4[2] ^ tsh) | (s4[3] ^ tsh) |          \
   (s5[0] ^ tsh) | (s5[1] ^ tsh) | (s5[2] ^ tsh) | (s5[3] ^ tsh) |          \
   (s6[0] ^ tsh) | (s6[1] ^ tsh) | (s6[2] ^ tsh) | (s6[3] ^ tsh) |          \
   (s7[0] ^ tsh) | (s7[1] ^ tsh) | (s7[2] ^ tsh) | (s7[3] ^ tsh))

// load j of a set covers dwords wave*2048 + j*256 + lane*4
//  -> row = wave*4 + (j>>1), col = (j&1)*256 + lane*4
// NOTE: macro locals prefixed stg_ to avoid colliding with caller's regs.
#define STAGE8(s0, s1, s2, s3, s4, s5, s6, s7)                   \
  {                                                              \
    const int stg_row = wave * 4;                                \
    const int stg_cA = lane * 4, stg_cB = 256 + lane * 4;        \
    u32x2v stg_p;                                                \
    stg_p[0] = (s0[0] & 0xffffu) | (s0[1] << 16);                \
    stg_p[1] = (s0[2] & 0xffffu) | (s0[3] << 16);                \
    *(u32x2v*)&h_lds[stg_row + 0][stg_cA] = stg_p;               \
    stg_p[0] = (s1[0] & 0xffffu) | (s1[1] << 16);                \
    stg_p[1] = (s1[2] & 0xffffu) | (s1[3] << 16);                \
    *(u32x2v*)&h_lds[stg_row + 0][stg_cB] = stg_p;               \
    stg_p[0] = (s2[0] & 0xffffu) | (s2[1] << 16);                \
    stg_p[1] = (s2[2] & 0xffffu) | (s2[3] << 16);                \
    *(u32x2v*)&h_lds[stg_row + 1][stg_cA] = stg_p;               \
    stg_p[0] = (s3[0] & 0xffffu) | (s3[1] << 16);                \
    stg_p[1] = (s3[2] & 0xffffu) | (s3[3] << 16);                \
    *(u32x2v*)&h_lds[stg_row + 1][stg_cB] = stg_p;               \
    stg_p[0] = (s4[0] & 0xffffu) | (s4[1] << 16);                \
    stg_p[1] = (s4[2] & 0xffffu) | (s4[3] << 16);                \
    *(u32x2v*)&h_lds[stg_row + 2][stg_cA] = stg_p;               \
    stg_p[0] = (s5[0] & 0xffffu) | (s5[1] << 16);                \
    stg_p[1] = (s5[2] & 0xffffu) | (s5[3] << 16);                \
    *(u32x2v*)&h_lds[stg_row + 2][stg_cB] = stg_p;               \
    stg_p[0] = (s6[0] & 0xffffu) | (s6[1] << 16);                \
    stg_p[1] = (s6[2] & 0xffffu) | (s6[3] << 16);                \
    *(u32x2v*)&h_lds[stg_row + 3][stg_cA] = stg_p;               \
    stg_p[0] = (s7[0] & 0xffffu) | (s7[1] << 16);                \
    stg_p[1] = (s7[2] & 0xffffu) | (s7[3] << 16);                \
    *(u32x2v*)&h_lds[stg_row + 3][stg_cB] = stg_p;               \
  }

#define WAITV(N)                                            \
  asm volatile("s_waitcnt vmcnt(" #N ")" ::: "memory");     \
  __builtin_amdgcn_sched_barrier(0)

__global__ __launch_bounds__(256, 1) void k_lstm(const unsigned short* __restrict__ xproj,
                                                 const unsigned short* __restrict__ Vt,
                                                 unsigned* __restrict__ sh,
                                                 float* __restrict__ out) {
  __shared__ unsigned short h_lds[16][520];       // [batch][d] bf16, padded
  __shared__ unsigned short xbuf[2][4][64][20];   // [dbuf][gate][d][batch+pad]

  int g = blockIdx.x;
  int bg = g >> 3, dgp = g & 7;
  int tid = threadIdx.x, wave = tid >> 6, lane = tid & 63;

  // V fragments: 4 gate-tiles x 16 k-steps, resident (256 VGPR)
  short8 vfrag[4][16];
#pragma unroll
  for (int q = 0; q < 4; ++q)
#pragma unroll
    for (int kt = 0; kt < 16; ++kt) {
      int n = q * 512 + dgp * 64 + wave * 16 + (lane & 15);
      vfrag[q][kt] = *(const short8*)(Vt + (size_t)n * 512 + kt * 32 + (lane >> 4) * 8);
    }

  // elementwise ownership: 4 batches x 1 d-col per lane (matches MFMA C map)
  int dl = wave * 16 + (lane & 15);      // d within wg tile [0,64)
  int dglob = dgp * 64 + dl;             // global d
  int b_lo = (lane >> 4) * 4;            // first of 4 batch rows
  int batch0 = bg * 16 + b_lo;
  float cst[4] = {0.f, 0.f, 0.f, 0.f};   // cell state in registers

  // x prefetch mapping: thread (xb, xq2, xs) loads gates 2*xq2, 2*xq2+1
  int xb = tid >> 4, xq2 = (tid >> 3) & 1, xs = tid & 7;
  const unsigned short* xrow0 =
      xproj + (size_t)(bg * 16 + xb) * 2048 + (xq2 * 2 + 0) * 512 + dgp * 64 + xs * 8;
  const unsigned short* xrow1 = xrow0 + 512;

  int arow = lane & 15, acol8 = (lane >> 4) * 8;  // MFMA A-fragment row/col

  // linear poll base: wave w, lane l -> dword bg*8192 + w*2048 + l*4
  const unsigned* pl0 = sh + (size_t)bg * 8192 + wave * 2048 + lane * 4;
  unsigned* hstore0 = sh + (size_t)batch0 * 512 + dglob;

  short8 xv0 = *(const short8*)xrow0;  // x for t=0
  short8 xv1 = *(const short8*)xrow1;

  for (int t = 0; t < 512; ++t) {
    // prefetch next step's x FIRST (overlaps poll RT; drained by barrier A)
    short8 xn0 = xv0, xn1 = xv1;
    if (t < 511) {
      xn0 = *(const short8*)(xrow0 + (size_t)(t + 1) * 131072);
      xn1 = *(const short8*)(xrow1 + (size_t)(t + 1) * 131072);
    }

    // ---- 2-set pipelined poll of stamped h(t) ----
    unsigned tsh = (unsigned)t << 16;
    const unsigned* pb = pl0 + ((t & 1) ? 32768 : 0);
    const unsigned* pb4 = pb + 1024;
    u32x4v q0, q1, q2, q3, q4, q5, q6, q7;
    u32x4v r0, r1, r2, r3, r4, r5, r6, r7;
    POLL_ISSUE(q0, q1, q2, q3, q4, q5, q6, q7);
    POLL_ISSUE(r0, r1, r2, r3, r4, r5, r6, r7);
    int use_r = 0;
    while (true) {
      WAITV(8);  // oldest set (Q-aged) done
      unsigned accq = POLL_CHECK(q0, q1, q2, q3, q4, q5, q6, q7);
      if (__all((accq >> 16) == 0)) { use_r = 0; break; }
      POLL_ISSUE(q0, q1, q2, q3, q4, q5, q6, q7);
      WAITV(8);  // now R is the oldest
      unsigned accr = POLL_CHECK(r0, r1, r2, r3, r4, r5, r6, r7);
      if (__all((accr >> 16) == 0)) { use_r = 1; break; }
      POLL_ISSUE(r0, r1, r2, r3, r4, r5, r6, r7);
    }
    WAITV(0);  // drain the losing set before its regs are clobbered/reused

    // ---- strip stamps, stage winning set into LDS ----
    if (use_r) {
      STAGE8(r0, r1, r2, r3, r4, r5, r6, r7);
    } else {
      STAGE8(q0, q1, q2, q3, q4, q5, q6, q7);
    }

    // ---- stage x(t) into xbuf[t&1]: [gate][d][batch] transposed ----
    {
      unsigned short* xp0 = &xbuf[t & 1][xq2 * 2 + 0][xs * 8][xb];
      unsigned short* xp1 = &xbuf[t & 1][xq2 * 2 + 1][xs * 8][xb];
#pragma unroll
      for (int j = 0; j < 8; ++j) {
        xp0[j * 20] = (unsigned short)xv0[j];
        xp1[j * 20] = (unsigned short)xv1[j];
      }
    }

    __syncthreads();  // barrier A: h_lds + xbuf staged

    // ---- recurrent GEMM: 4 gate-tiles, K=512 ----
    f32x4 a[4] = {};
#pragma unroll
    for (int kt = 0; kt < 16; ++kt) {
      short8 af = *(const short8*)&h_lds[arow][kt * 32 + acol8];
#pragma unroll
      for (int q = 0; q < 4; ++q)
        a[q] = __builtin_amdgcn_mfma_f32_16x16x32_bf16(af, vfrag[q][kt], a[q], 0, 0, 0);
    }

    // ---- in-register elementwise: lane owns 4 batches x 1 d-col ----
    ushort4v x0 = *(const ushort4v*)&xbuf[t & 1][0][dl][b_lo];
    ushort4v x1 = *(const ushort4v*)&xbuf[t & 1][1][dl][b_lo];
    ushort4v x2 = *(const ushort4v*)&xbuf[t & 1][2][dl][b_lo];
    ushort4v x3 = *(const ushort4v*)&xbuf[t & 1][3][dl][b_lo];

    unsigned st = (unsigned)(t + 1) << 16;
    unsigned sd[4];
    float hf[4];
#pragma unroll
    for (int rr = 0; rr < 4; ++rr) {
      float iv = sigm(a[0][rr] + bf2f(x0[rr]));
      float fv = sigm(a[1][rr] + bf2f(x1[rr]));
      float gv = tanh_f(a[2][rr] + bf2f(x2[rr]));
      float ov = sigm(a[3][rr] + bf2f(x3[rr]));
      cst[rr] = fv * cst[rr] + iv * gv;
      float hv = ov * tanh_f(cst[rr]);
      hf[rr] = hv;
      sd[rr] = (unsigned)f2bf(hv) | st;
    }

    // ---- stamped h publish: 4 rows, 2048B apart; offset imm max 4095 so
    //      rows 2,3 go through a second base reg (hp4 = hp + 4096B) ----
    {
      unsigned* hp = hstore0 + (((t + 1) & 1) ? 32768 : 0);
      unsigned* hp4 = hp + 1024;  // +4096 bytes
      asm volatile(
          "global_store_dword %0, %2, off sc0 sc1\n\t"
          "global_store_dword %0, %3, off offset:2048 sc0 sc1\n\t"
          "global_store_dword %1, %4, off sc0 sc1\n\t"
          "global_store_dword %1, %5, off offset:2048 sc0 sc1"
          :: "v"(hp), "v"(hp4), "v"(sd[0]), "v"(sd[1]), "v"(sd[2]), "v"(sd[3])
          : "memory");
    }

    // ---- hidden_seq (+ finals) ----
#pragma unroll
    for (int rr = 0; rr < 4; ++rr)
      out[(size_t)(batch0 + rr) * 262144 + (size_t)t * 512 + dglob] = hf[rr];
    if (t == 511) {
#pragma unroll
      for (int rr = 0; rr < 4; ++rr) {
        out[16777216 + (batch0 + rr) * 512 + dglob] = hf[rr];
        out[16809984 + (batch0 + rr) * 512 + dglob] = cst[rr];
      }
    }
    xv0 = xn0; xv1 = xn1;
    // no end-of-step barrier: stamped-store -> poll is the inter-step sync.
    // h_lds/xbuf overwrite safety: any wg's step-t+1 staging requires its
    // poll(t+1) success, which requires ALL threads of ALL group wgs to have
    // published h(t+1), which postdates their step-t LDS reads.
  }
}

extern "C" void kernel_launch(void* const* d_in, const int* in_sizes, int n_in,
                              void* d_out, int out_size, void* d_ws, size_t ws_size,
                              hipStream_t stream) {
  const float* cas  = (const float*)d_in[0];
  const float* soc  = (const float*)d_in[1];
  const float* W    = (const float*)d_in[2];
  const float* U    = (const float*)d_in[3];
  const float* V    = (const float*)d_in[4];
  const float* bias = (const float*)d_in[5];
  float* out = (float*)d_out;
  char* ws = (char*)d_ws;

  unsigned short* xproj = (unsigned short*)(ws + 262144);  // 134,217,728 B
  unsigned short* Xcat  = xproj + (size_t)32768 * 2048;    // 67,108,864 B
  unsigned short* WUt   = Xcat + (size_t)32768 * 1024;     // 4,194,304 B
  unsigned short* Vt    = WUt + (size_t)2048 * 1024;       // 2,097,152 B
  // stamped h buffer reuses the head of Xcat (dead after k_gemm): 256KB
  unsigned* sh = (unsigned*)Xcat;

  k_convX<<<16384, 256, 0, stream>>>(cas, soc, Xcat);
  k_transpose<<<dim3(16, 32), 256, 0, stream>>>(W, U, 512, 1024, WUt);
  k_transpose<<<dim3(8, 32), 256, 0, stream>>>(V, V, 512, 512, Vt);
  k_gemm<<<dim3(16, 256), 256, 0, stream>>>(Xcat, WUt, bias, xproj);
  // zero stamps (epoch 0, h = 0) for both ping-pong slots
  hipMemsetAsync(sh, 0, 262144, stream);
  k_lstm<<<32, 256, 0, stream>>>(xproj, Vt, sh, out);
}

// Round 9
// 1528.905 us; speedup vs baseline: 1.3039x; 1.3039x over previous
//
#include <hip/hip_runtime.h>
#include <stdint.h>

// SharedLSTM: B=64, S=512, D=512.
//  out = concat(hidden_seq [64,512,512], h_T [64,512], c_T [64,512]) fp32.
//
// Round 9 = round 5 (best verified: k_lstm 1180us) + 2-set pipelined poll
// ONLY. Round 8's bundled redesign (8wg-groups, in-reg elementwise,
// x-transpose LDS) regressed 1.5x: scalar stride-40B x-staging caused ~8-way
// bank conflicts (1.15e7 -> 1.89e7) on the critical path, occupancy halved,
// 4x scalar h-stores. Reverted; only the poll pipelining survives.
//
// Epoch-stamped protocol (rounds 4-5, proven): h stored as stamped dwords
// (bf16 h | epoch<<16) sc0 sc1, fire-and-forget; consumers poll the data
// itself until every stamp == t. Ping-pong slots; no flags, no fences.
//
// ws layout:
//   [262144, +134217728)  x_proj bf16 [32768][2048]
//   then Xcat (67MB) — head reused after k_gemm as stamped-h sh (256KB,
//        memset between k_gemm and k_lstm), WUt (4MB), Vt (2MB)

typedef __attribute__((ext_vector_type(8))) short short8;
typedef __attribute__((ext_vector_type(4))) float f32x4;
typedef __attribute__((ext_vector_type(2))) float f32x2;
typedef __attribute__((ext_vector_type(4))) unsigned int u32x4v;
typedef __attribute__((ext_vector_type(2))) unsigned int u32x2v;

__device__ __forceinline__ unsigned short f2bf(float x) {
  union { float f; unsigned v; } c; c.f = x;
  unsigned r = (c.v + 0x7fffu + ((c.v >> 16) & 1u)) >> 16;  // RNE
  return (unsigned short)r;
}
__device__ __forceinline__ float bf2f(unsigned short u) {
  union { unsigned v; float f; } c; c.v = (unsigned)u << 16; return c.f;
}
__device__ __forceinline__ float sigm(float x) { return 1.f / (1.f + __expf(-x)); }
__device__ __forceinline__ float tanh_f(float x) { return 1.f - 2.f / (__expf(2.f * x) + 1.f); }

// ---------------- 1) concat + fp32->bf16 ----------------
__global__ __launch_bounds__(256) void k_convX(const float* __restrict__ cas,
                                               const float* __restrict__ soc,
                                               unsigned short* __restrict__ Xcat) {
  size_t i = ((size_t)blockIdx.x * 256 + threadIdx.x) * 8;  // elem in 32768*1024
  int r = (int)(i >> 10), k0 = (int)(i & 1023);
  const float* src = (k0 < 512) ? cas + (size_t)r * 512 + k0
                                : soc + (size_t)r * 512 + (k0 - 512);
  f32x4 a = *(const f32x4*)src;
  f32x4 b = *(const f32x4*)(src + 4);
  short8 o;
  o[0] = (short)f2bf(a[0]); o[1] = (short)f2bf(a[1]);
  o[2] = (short)f2bf(a[2]); o[3] = (short)f2bf(a[3]);
  o[4] = (short)f2bf(b[0]); o[5] = (short)f2bf(b[1]);
  o[6] = (short)f2bf(b[2]); o[7] = (short)f2bf(b[3]);
  *(short8*)(Xcat + i) = o;
}

// ---------------- 2) transpose + convert: Out[n][kk] = src(kk,n) -----------
__global__ __launch_bounds__(256) void k_transpose(const float* __restrict__ S0,
                                                   const float* __restrict__ S1,
                                                   int split, int Ktot,
                                                   unsigned short* __restrict__ Out) {
  __shared__ float tile[64][65];
  int tk = blockIdx.x, tn = blockIdx.y, tid = threadIdx.x;
#pragma unroll
  for (int i = 0; i < 16; ++i) {
    int idx = i * 256 + tid;
    int kr = idx >> 6, nc = idx & 63;
    int kk = tk * 64 + kr;
    const float* s = (kk < split) ? S0 + (size_t)kk * 2048 + tn * 64 + nc
                                  : S1 + (size_t)(kk - split) * 2048 + tn * 64 + nc;
    tile[kr][nc] = *s;
  }
  __syncthreads();
#pragma unroll
  for (int i = 0; i < 16; ++i) {
    int idx = i * 256 + tid;
    int nr = idx >> 6, kc = idx & 63;
    Out[(size_t)(tn * 64 + nr) * Ktot + tk * 64 + kc] = f2bf(tile[kc][nr]);
  }
}

// ---------------- 3) x_proj GEMM: 128x128 tile, BK=32, global_load_lds ------
__global__ __launch_bounds__(256) void k_gemm(const unsigned short* __restrict__ A,
                                              const unsigned short* __restrict__ Bt,
                                              const float* __restrict__ bias,
                                              unsigned short* __restrict__ xproj) {
  __shared__ __attribute__((aligned(16))) unsigned short At[128 * 32];
  __shared__ __attribute__((aligned(16))) unsigned short Bs[128 * 32];
  int tn0 = blockIdx.x * 128, tm0 = blockIdx.y * 128;
  int tid = threadIdx.x, wave = tid >> 6, lane = tid & 63;
  int wr = wave >> 1, wc = wave & 1;
  f32x4 acc[4][4] = {};

  for (int kt = 0; kt < 32; ++kt) {
    __syncthreads();
#pragma unroll
    for (int i = 0; i < 2; ++i) {
      int cb = i * 256 + wave * 64;
      int c = cb + lane;
      const unsigned short* ga = A + (size_t)(tm0 + (c >> 2)) * 1024 + kt * 32 + (c & 3) * 8;
      __builtin_amdgcn_global_load_lds((const __attribute__((address_space(1))) void*)ga,
                                       (__attribute__((address_space(3))) void*)(At + cb * 8),
                                       16, 0, 0);
      const unsigned short* gb = Bt + (size_t)(tn0 + (c >> 2)) * 1024 + kt * 32 + (c & 3) * 8;
      __builtin_amdgcn_global_load_lds((const __attribute__((address_space(1))) void*)gb,
                                       (__attribute__((address_space(3))) void*)(Bs + cb * 8),
                                       16, 0, 0);
    }
    __syncthreads();
    short8 af[4], bf[4];
#pragma unroll
    for (int m = 0; m < 4; ++m)
      af[m] = *(const short8*)(At + (wr * 64 + m * 16 + (lane & 15)) * 32 + (lane >> 4) * 8);
#pragma unroll
    for (int n = 0; n < 4; ++n)
      bf[n] = *(const short8*)(Bs + (wc * 64 + n * 16 + (lane & 15)) * 32 + (lane >> 4) * 8);
#pragma unroll
    for (int m = 0; m < 4; ++m)
#pragma unroll
      for (int n = 0; n < 4; ++n)
        acc[m][n] = __builtin_amdgcn_mfma_f32_16x16x32_bf16(af[m], bf[n], acc[m][n], 0, 0, 0);
  }

#pragma unroll
  for (int n = 0; n < 4; ++n) {
    int cg = tn0 + wc * 64 + n * 16 + (lane & 15);
    float bv = bias[cg];
#pragma unroll
    for (int m = 0; m < 4; ++m) {
#pragma unroll
      for (int rr = 0; rr < 4; ++rr) {
        int rg = tm0 + wr * 64 + m * 16 + ((lane >> 4) << 2) + rr;  // r = b*512+s
        int orow = ((rg & 511) << 6) | (rg >> 9);                   // s*64+b
        xproj[(size_t)orow * 2048 + cg] = f2bf(acc[m][n][rr] + bv);
      }
    }
  }
}

// ---------------- 4) persistent recurrence, epoch-stamped ----------------
// wg = (bg = blockIdx>>4, dg = blockIdx&15). Group = 16 wgs sharing bg.
// wave w = gate w; owns V^T rows [w*512+dg*32, +32) (vfrag[2][16]).
// sh dwords: sh[slot][batch][d] = (bf16 h) | (epoch<<16).
// Wave w polls the LINEAR slab rows [bg*16+4w, +4) x 512 d (8KB), fully
// coalesced, with a 2-SET PIPELINED poll; stages into LDS.

#define POLL_ISSUE(s0, s1, s2, s3, s4, s5, s6, s7)                        \
  asm volatile(                                                           \
      "global_load_dwordx4 %0, %8, off sc0 sc1\n\t"                       \
      "global_load_dwordx4 %1, %8, off offset:1024 sc0 sc1\n\t"           \
      "global_load_dwordx4 %2, %8, off offset:2048 sc0 sc1\n\t"           \
      "global_load_dwordx4 %3, %8, off offset:3072 sc0 sc1\n\t"           \
      "global_load_dwordx4 %4, %9, off sc0 sc1\n\t"                       \
      "global_load_dwordx4 %5, %9, off offset:1024 sc0 sc1\n\t"           \
      "global_load_dwordx4 %6, %9, off offset:2048 sc0 sc1\n\t"           \
      "global_load_dwordx4 %7, %9, off offset:3072 sc0 sc1"               \
      : "=&v"(s0), "=&v"(s1), "=&v"(s2), "=&v"(s3), "=&v"(s4), "=&v"(s5), \
        "=&v"(s6), "=&v"(s7)                                              \
      : "v"(pb), "v"(pb4)                                                 \
      : "memory")

#define POLL_CHECK(s0, s1, s2, s3, s4, s5, s6, s7)                          \
  ((s0[0] ^ tsh) | (s0[1] ^ tsh) | (s0[2] ^ tsh) | (s0[3] ^ tsh) |          \
   (s1[0] ^ tsh) | (s1[1] ^ tsh) | (s1[2] ^ tsh) | (s1[3] ^ tsh) |          \
   (s2[0] ^ tsh) | (s2[1] ^ tsh) | (s2[2] ^ tsh) | (s2[3] ^ tsh) |          \
   (s3[0] ^ tsh) | (s3[1] ^ tsh) | (s3[2] ^ tsh) | (s3[3] ^ tsh) |          \
   (s4[0] ^ tsh) | (s4[1] ^ tsh) | (s4[2] ^ tsh) | (s4[3] ^ tsh) |          \
   (s5[0] ^ tsh) | (s5[1] ^ tsh) | (s5[2] ^ tsh) | (s5[3] ^ tsh) |          \
   (s6[0] ^ tsh) | (s6[1] ^ tsh) | (s6[2] ^ tsh) | (s6[3] ^ tsh) |          \
   (s7[0] ^ tsh) | (s7[1] ^ tsh) | (s7[2] ^ tsh) | (s7[3] ^ tsh))

// load j of a set covers dwords wave*2048 + j*256 + lane*4
//  -> row = wave*4 + (j>>1), col = (j&1)*256 + lane*4
#define STAGE8(s0, s1, s2, s3, s4, s5, s6, s7)                   \
  {                                                              \
    const int stg_row = wave * 4;                                \
    const int stg_cA = lane * 4, stg_cB = 256 + lane * 4;        \
    u32x2v stg_p;                                                \
    stg_p[0] = (s0[0] & 0xffffu) | (s0[1] << 16);                \
    stg_p[1] = (s0[2] & 0xffffu) | (s0[3] << 16);                \
    *(u32x2v*)&h_lds[stg_row + 0][stg_cA] = stg_p;               \
    stg_p[0] = (s1[0] & 0xffffu) | (s1[1] << 16);                \
    stg_p[1] = (s1[2] & 0xffffu) | (s1[3] << 16);                \
    *(u32x2v*)&h_lds[stg_row + 0][stg_cB] = stg_p;               \
    stg_p[0] = (s2[0] & 0xffffu) | (s2[1] << 16);                \
    stg_p[1] = (s2[2] & 0xffffu) | (s2[3] << 16);                \
    *(u32x2v*)&h_lds[stg_row + 1][stg_cA] = stg_p;               \
    stg_p[0] = (s3[0] & 0xffffu) | (s3[1] << 16);                \
    stg_p[1] = (s3[2] & 0xffffu) | (s3[3] << 16);                \
    *(u32x2v*)&h_lds[stg_row + 1][stg_cB] = stg_p;               \
    stg_p[0] = (s4[0] & 0xffffu) | (s4[1] << 16);                \
    stg_p[1] = (s4[2] & 0xffffu) | (s4[3] << 16);                \
    *(u32x2v*)&h_lds[stg_row + 2][stg_cA] = stg_p;               \
    stg_p[0] = (s5[0] & 0xffffu) | (s5[1] << 16);                \
    stg_p[1] = (s5[2] & 0xffffu) | (s5[3] << 16);                \
    *(u32x2v*)&h_lds[stg_row + 2][stg_cB] = stg_p;               \
    stg_p[0] = (s6[0] & 0xffffu) | (s6[1] << 16);                \
    stg_p[1] = (s6[2] & 0xffffu) | (s6[3] << 16);                \
    *(u32x2v*)&h_lds[stg_row + 3][stg_cA] = stg_p;               \
    stg_p[0] = (s7[0] & 0xffffu) | (s7[1] << 16);                \
    stg_p[1] = (s7[2] & 0xffffu) | (s7[3] << 16);                \
    *(u32x2v*)&h_lds[stg_row + 3][stg_cB] = stg_p;               \
  }

#define WAITV(N)                                            \
  asm volatile("s_waitcnt vmcnt(" #N ")" ::: "memory");     \
  __builtin_amdgcn_sched_barrier(0)

__global__ __launch_bounds__(256, 1) void k_lstm(const unsigned short* __restrict__ xproj,
                                                 const unsigned short* __restrict__ Vt,
                                                 unsigned* __restrict__ sh,
                                                 float* __restrict__ out) {
  __shared__ unsigned short h_lds[16][520];   // 1040B rows: 16B-aligned
  __shared__ float gbuf[4][16][32];
  __shared__ __attribute__((aligned(16))) unsigned short xbuf[4][16][32];

  int g = blockIdx.x;
  int bg = g >> 4, dg = g & 15;
  int tid = threadIdx.x, wave = tid >> 6, lane = tid & 63;

  // V fragments resident across the whole kernel: 2 tiles x 16 k-steps
  short8 vfrag[2][16];
#pragma unroll
  for (int hh = 0; hh < 2; ++hh)
#pragma unroll
    for (int kt = 0; kt < 16; ++kt) {
      int n = wave * 512 + dg * 32 + hh * 16 + (lane & 15);
      vfrag[hh][kt] = *(const short8*)(Vt + (size_t)n * 512 + kt * 32 + (lane >> 4) * 8);
    }

  float c0 = 0.f, c1 = 0.f;          // cell state in registers
  int br = tid >> 4;                 // batch row 0..15
  int dc = (tid & 15) * 2;           // d col (pair)
  int batch = bg * 16 + br;
  int dglob = dg * 32 + dc;

  int xb = tid >> 4, xq = (tid >> 2) & 3, xs = tid & 3;
  const unsigned short* xrow =
      xproj + (size_t)(bg * 16 + xb) * 2048 + xq * 512 + dg * 32 + xs * 8;

  int arow = lane & 15, acol8 = (lane >> 4) * 8;   // MFMA fragment row/col-base

  // linear poll base: wave w, lane l -> dword (bg*16)*512 + w*2048 + l*4
  const unsigned* pl0 = sh + (size_t)bg * 8192 + wave * 2048 + lane * 4;
  unsigned* hstore0 = sh + (size_t)batch * 512 + dglob;   // producer base

  short8 xv = *(const short8*)xrow;  // x_proj for t=0

  for (int t = 0; t < 512; ++t) {
    // ---- prefetch next step's x_proj FIRST: overlaps the poll RT ----
    short8 xvn = xv;
    if (t < 511) xvn = *(const short8*)(xrow + (size_t)(t + 1) * 131072);

    // ---- 2-set pipelined poll of stamped h(t) ----
    // vmcnt bookkeeping: x prefetch (1 load, oldest) + Q(8) + R(8) = 17.
    // WAITV(8) retires x+Q in order -> check Q; on miss reissue Q, WAITV(8)
    // retires R -> check R; alternate. Winner staged after WAITV(0).
    unsigned tsh = (unsigned)t << 16;
    const unsigned* pb = pl0 + ((t & 1) ? 32768 : 0);   // slot = 64*512 dwords
    const unsigned* pb4 = pb + 1024;                    // +4096B
    u32x4v q0, q1, q2, q3, q4, q5, q6, q7;
    u32x4v r0, r1, r2, r3, r4, r5, r6, r7;
    POLL_ISSUE(q0, q1, q2, q3, q4, q5, q6, q7);
    POLL_ISSUE(r0, r1, r2, r3, r4, r5, r6, r7);
    int use_r = 0;
    while (true) {
      WAITV(8);  // oldest outstanding set done (plus x prefetch first time)
      unsigned accq = POLL_CHECK(q0, q1, q2, q3, q4, q5, q6, q7);
      if (__all((accq >> 16) == 0)) { use_r = 0; break; }
      POLL_ISSUE(q0, q1, q2, q3, q4, q5, q6, q7);
      WAITV(8);  // now R is the oldest
      unsigned accr = POLL_CHECK(r0, r1, r2, r3, r4, r5, r6, r7);
      if (__all((accr >> 16) == 0)) { use_r = 1; break; }
      POLL_ISSUE(r0, r1, r2, r3, r4, r5, r6, r7);
    }
    WAITV(0);  // drain the losing set before registers are reused

    // ---- strip stamps, stage winning set into LDS ----
    if (use_r) {
      STAGE8(r0, r1, r2, r3, r4, r5, r6, r7);
    } else {
      STAGE8(q0, q1, q2, q3, q4, q5, q6, q7);
    }

    __syncthreads();   // barrier A: h_lds fully staged

    // ---- recurrent GEMM: A = h fragments from LDS, B = resident V ----
    f32x4 a0 = {0.f, 0.f, 0.f, 0.f}, a1 = {0.f, 0.f, 0.f, 0.f};
#pragma unroll
    for (int kt = 0; kt < 16; ++kt) {
      short8 af = *(const short8*)&h_lds[arow][kt * 32 + acol8];
      a0 = __builtin_amdgcn_mfma_f32_16x16x32_bf16(af, vfrag[0][kt], a0, 0, 0, 0);
      a1 = __builtin_amdgcn_mfma_f32_16x16x32_bf16(af, vfrag[1][kt], a1, 0, 0, 0);
    }

    *(short8*)&xbuf[xq][xb][xs * 8] = xv;
#pragma unroll
    for (int rr = 0; rr < 4; ++rr) {
      gbuf[wave][((lane >> 4) << 2) + rr][lane & 15] = a0[rr];
      gbuf[wave][((lane >> 4) << 2) + rr][16 + (lane & 15)] = a1[rr];
    }
    __syncthreads();   // barrier B: gates ready

    // ---- elementwise: 2 (b,d) elems per thread ----
    f32x2 vi = *(const f32x2*)&gbuf[0][br][dc];
    f32x2 vf = *(const f32x2*)&gbuf[1][br][dc];
    f32x2 vg = *(const f32x2*)&gbuf[2][br][dc];
    f32x2 vo = *(const f32x2*)&gbuf[3][br][dc];
    unsigned xi = *(const unsigned*)&xbuf[0][br][dc];
    unsigned xf = *(const unsigned*)&xbuf[1][br][dc];
    unsigned xg = *(const unsigned*)&xbuf[2][br][dc];
    unsigned xo = *(const unsigned*)&xbuf[3][br][dc];

    float i0 = sigm(vi[0] + bf2f((unsigned short)xi));
    float i1 = sigm(vi[1] + bf2f((unsigned short)(xi >> 16)));
    float f0v = sigm(vf[0] + bf2f((unsigned short)xf));
    float f1v = sigm(vf[1] + bf2f((unsigned short)(xf >> 16)));
    float g0 = tanh_f(vg[0] + bf2f((unsigned short)xg));
    float g1 = tanh_f(vg[1] + bf2f((unsigned short)(xg >> 16)));
    float o0 = sigm(vo[0] + bf2f((unsigned short)xo));
    float o1 = sigm(vo[1] + bf2f((unsigned short)(xo >> 16)));

    c0 = f0v * c0 + i0 * g0;
    c1 = f1v * c1 + i1 * g1;
    float h0 = o0 * tanh_f(c0);
    float h1 = o1 * tanh_f(c1);

    // ---- stamped h publish: fire-and-forget, device scope ----
    unsigned st = (unsigned)(t + 1) << 16;
    u32x2v sd;
    sd[0] = (unsigned)f2bf(h0) | st;
    sd[1] = (unsigned)f2bf(h1) | st;
    unsigned* hp = hstore0 + (((t + 1) & 1) ? 32768 : 0);
    asm volatile("global_store_dwordx2 %0, %1, off sc0 sc1"
                 :: "v"(hp), "v"(sd) : "memory");

    f32x2 hv = {h0, h1};
    *(f32x2*)(out + (size_t)batch * 262144 + (size_t)t * 512 + dglob) = hv;
    if (t == 511) {
      *(f32x2*)(out + 16777216 + batch * 512 + dglob) = hv;
      f32x2 cv = {c0, c1};
      *(f32x2*)(out + 16809984 + batch * 512 + dglob) = cv;
    }
    xv = xvn;
    // no end-of-step barrier: stamped-store -> poll is the inter-step sync.
  }
}

extern "C" void kernel_launch(void* const* d_in, const int* in_sizes, int n_in,
                              void* d_out, int out_size, void* d_ws, size_t ws_size,
                              hipStream_t stream) {
  const float* cas  = (const float*)d_in[0];
  const float* soc  = (const float*)d_in[1];
  const float* W    = (const float*)d_in[2];
  const float* U    = (const float*)d_in[3];
  const float* V    = (const float*)d_in[4];
  const float* bias = (const float*)d_in[5];
  float* out = (float*)d_out;
  char* ws = (char*)d_ws;

  unsigned short* xproj = (unsigned short*)(ws + 262144);  // 134,217,728 B
  unsigned short* Xcat  = xproj + (size_t)32768 * 2048;    // 67,108,864 B
  unsigned short* WUt   = Xcat + (size_t)32768 * 1024;     // 4,194,304 B
  unsigned short* Vt    = WUt + (size_t)2048 * 1024;       // 2,097,152 B
  // stamped h buffer reuses the head of Xcat (dead after k_gemm): 256KB
  unsigned* sh = (unsigned*)Xcat;

  k_convX<<<16384, 256, 0, stream>>>(cas, soc, Xcat);
  k_transpose<<<dim3(16, 32), 256, 0, stream>>>(W, U, 512, 1024, WUt);
  k_transpose<<<dim3(8, 32), 256, 0, stream>>>(V, V, 512, 512, Vt);
  k_gemm<<<dim3(16, 256), 256, 0, stream>>>(Xcat, WUt, bias, xproj);
  // zero stamps (epoch 0, h = 0) for both ping-pong slots
  hipMemsetAsync(sh, 0, 262144, stream);
  k_lstm<<<64, 256, 0, stream>>>(xproj, Vt, sh, out);
}

// Round 10
// 1511.193 us; speedup vs baseline: 1.3192x; 1.0117x over previous
//
#include <hip/hip_runtime.h>
#include <stdint.h>

// SharedLSTM: B=64, S=512, D=512.
//  out = concat(hidden_seq [64,512,512], h_T [64,512], c_T [64,512]) fp32.
//
// Round 10 = round 9 (2-set pipelined poll) with the post-detect drain
// removed from the critical path:
//  - no WAITV(0) after detection (winner is already retired by WAITV(8));
//  - RAW barriers (s_waitcnt lgkmcnt(0); s_barrier) instead of
//    __syncthreads, whose implicit vmcnt(0) was draining the losing poll
//    set (up to a full RT) every step — this is what made round 9 regress;
//  - keep-alive asm pins both poll sets' registers across the iteration so
//    pending returns can't land in reallocated regs (in-order vmcnt
//    writeback makes reissue-over-outstanding safe).
//
// Epoch-stamped protocol (rounds 4-5, proven): h stored as stamped dwords
// (bf16 h | epoch<<16) sc0 sc1, fire-and-forget; consumers poll the data
// itself until every stamp == t. Ping-pong slots; no flags, no fences.
//
// ws layout:
//   [262144, +134217728)  x_proj bf16 [32768][2048]
//   then Xcat (67MB) — head reused after k_gemm as stamped-h sh (256KB,
//        memset between k_gemm and k_lstm), WUt (4MB), Vt (2MB)

typedef __attribute__((ext_vector_type(8))) short short8;
typedef __attribute__((ext_vector_type(4))) float f32x4;
typedef __attribute__((ext_vector_type(2))) float f32x2;
typedef __attribute__((ext_vector_type(4))) unsigned int u32x4v;
typedef __attribute__((ext_vector_type(2))) unsigned int u32x2v;

__device__ __forceinline__ unsigned short f2bf(float x) {
  union { float f; unsigned v; } c; c.f = x;
  unsigned r = (c.v + 0x7fffu + ((c.v >> 16) & 1u)) >> 16;  // RNE
  return (unsigned short)r;
}
__device__ __forceinline__ float bf2f(unsigned short u) {
  union { unsigned v; float f; } c; c.v = (unsigned)u << 16; return c.f;
}
__device__ __forceinline__ float sigm(float x) { return 1.f / (1.f + __expf(-x)); }
__device__ __forceinline__ float tanh_f(float x) { return 1.f - 2.f / (__expf(2.f * x) + 1.f); }

// ---------------- 1) concat + fp32->bf16 ----------------
__global__ __launch_bounds__(256) void k_convX(const float* __restrict__ cas,
                                               const float* __restrict__ soc,
                                               unsigned short* __restrict__ Xcat) {
  size_t i = ((size_t)blockIdx.x * 256 + threadIdx.x) * 8;  // elem in 32768*1024
  int r = (int)(i >> 10), k0 = (int)(i & 1023);
  const float* src = (k0 < 512) ? cas + (size_t)r * 512 + k0
                                : soc + (size_t)r * 512 + (k0 - 512);
  f32x4 a = *(const f32x4*)src;
  f32x4 b = *(const f32x4*)(src + 4);
  short8 o;
  o[0] = (short)f2bf(a[0]); o[1] = (short)f2bf(a[1]);
  o[2] = (short)f2bf(a[2]); o[3] = (short)f2bf(a[3]);
  o[4] = (short)f2bf(b[0]); o[5] = (short)f2bf(b[1]);
  o[6] = (short)f2bf(b[2]); o[7] = (short)f2bf(b[3]);
  *(short8*)(Xcat + i) = o;
}

// ---------------- 2) transpose + convert: Out[n][kk] = src(kk,n) -----------
__global__ __launch_bounds__(256) void k_transpose(const float* __restrict__ S0,
                                                   const float* __restrict__ S1,
                                                   int split, int Ktot,
                                                   unsigned short* __restrict__ Out) {
  __shared__ float tile[64][65];
  int tk = blockIdx.x, tn = blockIdx.y, tid = threadIdx.x;
#pragma unroll
  for (int i = 0; i < 16; ++i) {
    int idx = i * 256 + tid;
    int kr = idx >> 6, nc = idx & 63;
    int kk = tk * 64 + kr;
    const float* s = (kk < split) ? S0 + (size_t)kk * 2048 + tn * 64 + nc
                                  : S1 + (size_t)(kk - split) * 2048 + tn * 64 + nc;
    tile[kr][nc] = *s;
  }
  __syncthreads();
#pragma unroll
  for (int i = 0; i < 16; ++i) {
    int idx = i * 256 + tid;
    int nr = idx >> 6, kc = idx & 63;
    Out[(size_t)(tn * 64 + nr) * Ktot + tk * 64 + kc] = f2bf(tile[kc][nr]);
  }
}

// ---------------- 3) x_proj GEMM: 128x128 tile, BK=32, global_load_lds ------
__global__ __launch_bounds__(256) void k_gemm(const unsigned short* __restrict__ A,
                                              const unsigned short* __restrict__ Bt,
                                              const float* __restrict__ bias,
                                              unsigned short* __restrict__ xproj) {
  __shared__ __attribute__((aligned(16))) unsigned short At[128 * 32];
  __shared__ __attribute__((aligned(16))) unsigned short Bs[128 * 32];
  int tn0 = blockIdx.x * 128, tm0 = blockIdx.y * 128;
  int tid = threadIdx.x, wave = tid >> 6, lane = tid & 63;
  int wr = wave >> 1, wc = wave & 1;
  f32x4 acc[4][4] = {};

  for (int kt = 0; kt < 32; ++kt) {
    __syncthreads();
#pragma unroll
    for (int i = 0; i < 2; ++i) {
      int cb = i * 256 + wave * 64;
      int c = cb + lane;
      const unsigned short* ga = A + (size_t)(tm0 + (c >> 2)) * 1024 + kt * 32 + (c & 3) * 8;
      __builtin_amdgcn_global_load_lds((const __attribute__((address_space(1))) void*)ga,
                                       (__attribute__((address_space(3))) void*)(At + cb * 8),
                                       16, 0, 0);
      const unsigned short* gb = Bt + (size_t)(tn0 + (c >> 2)) * 1024 + kt * 32 + (c & 3) * 8;
      __builtin_amdgcn_global_load_lds((const __attribute__((address_space(1))) void*)gb,
                                       (__attribute__((address_space(3))) void*)(Bs + cb * 8),
                                       16, 0, 0);
    }
    __syncthreads();
    short8 af[4], bf[4];
#pragma unroll
    for (int m = 0; m < 4; ++m)
      af[m] = *(const short8*)(At + (wr * 64 + m * 16 + (lane & 15)) * 32 + (lane >> 4) * 8);
#pragma unroll
    for (int n = 0; n < 4; ++n)
      bf[n] = *(const short8*)(Bs + (wc * 64 + n * 16 + (lane & 15)) * 32 + (lane >> 4) * 8);
#pragma unroll
    for (int m = 0; m < 4; ++m)
#pragma unroll
      for (int n = 0; n < 4; ++n)
        acc[m][n] = __builtin_amdgcn_mfma_f32_16x16x32_bf16(af[m], bf[n], acc[m][n], 0, 0, 0);
  }

#pragma unroll
  for (int n = 0; n < 4; ++n) {
    int cg = tn0 + wc * 64 + n * 16 + (lane & 15);
    float bv = bias[cg];
#pragma unroll
    for (int m = 0; m < 4; ++m) {
#pragma unroll
      for (int rr = 0; rr < 4; ++rr) {
        int rg = tm0 + wr * 64 + m * 16 + ((lane >> 4) << 2) + rr;  // r = b*512+s
        int orow = ((rg & 511) << 6) | (rg >> 9);                   // s*64+b
        xproj[(size_t)orow * 2048 + cg] = f2bf(acc[m][n][rr] + bv);
      }
    }
  }
}

// ---------------- 4) persistent recurrence, epoch-stamped ----------------
// wg = (bg = blockIdx>>4, dg = blockIdx&15). Group = 16 wgs sharing bg.
// wave w = gate w; owns V^T rows [w*512+dg*32, +32) (vfrag[2][16]).
// sh dwords: sh[slot][batch][d] = (bf16 h) | (epoch<<16).

#define POLL_ISSUE(s0, s1, s2, s3, s4, s5, s6, s7)                        \
  asm volatile(                                                           \
      "global_load_dwordx4 %0, %8, off sc0 sc1\n\t"                       \
      "global_load_dwordx4 %1, %8, off offset:1024 sc0 sc1\n\t"           \
      "global_load_dwordx4 %2, %8, off offset:2048 sc0 sc1\n\t"           \
      "global_load_dwordx4 %3, %8, off offset:3072 sc0 sc1\n\t"           \
      "global_load_dwordx4 %4, %9, off sc0 sc1\n\t"                       \
      "global_load_dwordx4 %5, %9, off offset:1024 sc0 sc1\n\t"           \
      "global_load_dwordx4 %6, %9, off offset:2048 sc0 sc1\n\t"           \
      "global_load_dwordx4 %7, %9, off offset:3072 sc0 sc1"               \
      : "=&v"(s0), "=&v"(s1), "=&v"(s2), "=&v"(s3), "=&v"(s4), "=&v"(s5), \
        "=&v"(s6), "=&v"(s7)                                              \
      : "v"(pb), "v"(pb4)                                                 \
      : "memory")

#define POLL_CHECK(s0, s1, s2, s3, s4, s5, s6, s7)                          \
  ((s0[0] ^ tsh) | (s0[1] ^ tsh) | (s0[2] ^ tsh) | (s0[3] ^ tsh) |          \
   (s1[0] ^ tsh) | (s1[1] ^ tsh) | (s1[2] ^ tsh) | (s1[3] ^ tsh) |          \
   (s2[0] ^ tsh) | (s2[1] ^ tsh) | (s2[2] ^ tsh) | (s2[3] ^ tsh) |          \
   (s3[0] ^ tsh) | (s3[1] ^ tsh) | (s3[2] ^ tsh) | (s3[3] ^ tsh) |          \
   (s4[0] ^ tsh) | (s4[1] ^ tsh) | (s4[2] ^ tsh) | (s4[3] ^ tsh) |          \
   (s5[0] ^ tsh) | (s5[1] ^ tsh) | (s5[2] ^ tsh) | (s5[3] ^ tsh) |          \
   (s6[0] ^ tsh) | (s6[1] ^ tsh) | (s6[2] ^ tsh) | (s6[3] ^ tsh) |          \
   (s7[0] ^ tsh) | (s7[1] ^ tsh) | (s7[2] ^ tsh) | (s7[3] ^ tsh))

// load j of a set covers dwords wave*2048 + j*256 + lane*4
//  -> row = wave*4 + (j>>1), col = (j&1)*256 + lane*4
#define STAGE8(s0, s1, s2, s3, s4, s5, s6, s7)                   \
  {                                                              \
    const int stg_row = wave * 4;                                \
    const int stg_cA = lane * 4, stg_cB = 256 + lane * 4;        \
    u32x2v stg_p;                                                \
    stg_p[0] = (s0[0] & 0xffffu) | (s0[1] << 16);                \
    stg_p[1] = (s0[2] & 0xffffu) | (s0[3] << 16);                \
    *(u32x2v*)&h_lds[stg_row + 0][stg_cA] = stg_p;               \
    stg_p[0] = (s1[0] & 0xffffu) | (s1[1] << 16);                \
    stg_p[1] = (s1[2] & 0xffffu) | (s1[3] << 16);                \
    *(u32x2v*)&h_lds[stg_row + 0][stg_cB] = stg_p;               \
    stg_p[0] = (s2[0] & 0xffffu) | (s2[1] << 16);                \
    stg_p[1] = (s2[2] & 0xffffu) | (s2[3] << 16);                \
    *(u32x2v*)&h_lds[stg_row + 1][stg_cA] = stg_p;               \
    stg_p[0] = (s3[0] & 0xffffu) | (s3[1] << 16);                \
    stg_p[1] = (s3[2] & 0xffffu) | (s3[3] << 16);                \
    *(u32x2v*)&h_lds[stg_row + 1][stg_cB] = stg_p;               \
    stg_p[0] = (s4[0] & 0xffffu) | (s4[1] << 16);                \
    stg_p[1] = (s4[2] & 0xffffu) | (s4[3] << 16);                \
    *(u32x2v*)&h_lds[stg_row + 2][stg_cA] = stg_p;               \
    stg_p[0] = (s5[0] & 0xffffu) | (s5[1] << 16);                \
    stg_p[1] = (s5[2] & 0xffffu) | (s5[3] << 16);                \
    *(u32x2v*)&h_lds[stg_row + 2][stg_cB] = stg_p;               \
    stg_p[0] = (s6[0] & 0xffffu) | (s6[1] << 16);                \
    stg_p[1] = (s6[2] & 0xffffu) | (s6[3] << 16);                \
    *(u32x2v*)&h_lds[stg_row + 3][stg_cA] = stg_p;               \
    stg_p[0] = (s7[0] & 0xffffu) | (s7[1] << 16);                \
    stg_p[1] = (s7[2] & 0xffffu) | (s7[3] << 16);                \
    *(u32x2v*)&h_lds[stg_row + 3][stg_cB] = stg_p;               \
  }

#define WAITV(N)                                            \
  asm volatile("s_waitcnt vmcnt(" #N ")" ::: "memory");     \
  __builtin_amdgcn_sched_barrier(0)

// raw barrier: LDS ordering only (lgkmcnt), NO vmcnt(0) drain
#define BARRIER_LDS()                                               \
  __builtin_amdgcn_sched_barrier(0);                                \
  asm volatile("s_waitcnt lgkmcnt(0)\n\ts_barrier" ::: "memory");   \
  __builtin_amdgcn_sched_barrier(0)

__global__ __launch_bounds__(256, 1) void k_lstm(const unsigned short* __restrict__ xproj,
                                                 const unsigned short* __restrict__ Vt,
                                                 unsigned* __restrict__ sh,
                                                 float* __restrict__ out) {
  __shared__ unsigned short h_lds[16][520];   // 1040B rows: 16B-aligned
  __shared__ float gbuf[4][16][32];
  __shared__ __attribute__((aligned(16))) unsigned short xbuf[4][16][32];

  int g = blockIdx.x;
  int bg = g >> 4, dg = g & 15;
  int tid = threadIdx.x, wave = tid >> 6, lane = tid & 63;

  // V fragments resident across the whole kernel: 2 tiles x 16 k-steps
  short8 vfrag[2][16];
#pragma unroll
  for (int hh = 0; hh < 2; ++hh)
#pragma unroll
    for (int kt = 0; kt < 16; ++kt) {
      int n = wave * 512 + dg * 32 + hh * 16 + (lane & 15);
      vfrag[hh][kt] = *(const short8*)(Vt + (size_t)n * 512 + kt * 32 + (lane >> 4) * 8);
    }

  float c0 = 0.f, c1 = 0.f;          // cell state in registers
  int br = tid >> 4;                 // batch row 0..15
  int dc = (tid & 15) * 2;           // d col (pair)
  int batch = bg * 16 + br;
  int dglob = dg * 32 + dc;

  int xb = tid >> 4, xq = (tid >> 2) & 3, xs = tid & 3;
  const unsigned short* xrow =
      xproj + (size_t)(bg * 16 + xb) * 2048 + xq * 512 + dg * 32 + xs * 8;

  int arow = lane & 15, acol8 = (lane >> 4) * 8;   // MFMA fragment row/col-base

  // linear poll base: wave w, lane l -> dword (bg*16)*512 + w*2048 + l*4
  const unsigned* pl0 = sh + (size_t)bg * 8192 + wave * 2048 + lane * 4;
  unsigned* hstore0 = sh + (size_t)batch * 512 + dglob;   // producer base

  short8 xv = *(const short8*)xrow;  // x_proj for t=0

  for (int t = 0; t < 512; ++t) {
    // ---- prefetch next step's x_proj FIRST: overlaps the poll RT; it is
    //      retired by the first WAITV(8) (everything but newest 8 retires)
    short8 xvn = xv;
    if (t < 511) xvn = *(const short8*)(xrow + (size_t)(t + 1) * 131072);

    // ---- 2-set pipelined poll of stamped h(t) ----
    // WAITV(8) = "retire everything except the newest 8 loads" — robust to
    // leftovers (prior losing set, store acks, x prefetch). The set just
    // checked is always fully retired; the other set is the newest 8.
    unsigned tsh = (unsigned)t << 16;
    const unsigned* pb = pl0 + ((t & 1) ? 32768 : 0);   // slot = 64*512 dwords
    const unsigned* pb4 = pb + 1024;                    // +4096B
    u32x4v q0, q1, q2, q3, q4, q5, q6, q7;
    u32x4v r0, r1, r2, r3, r4, r5, r6, r7;
    POLL_ISSUE(q0, q1, q2, q3, q4, q5, q6, q7);
    POLL_ISSUE(r0, r1, r2, r3, r4, r5, r6, r7);
    int use_r = 0;
    while (true) {
      WAITV(8);  // Q retired (R is the newest 8)
      unsigned accq = POLL_CHECK(q0, q1, q2, q3, q4, q5, q6, q7);
      if (__all((accq >> 16) == 0)) { use_r = 0; break; }
      POLL_ISSUE(q0, q1, q2, q3, q4, q5, q6, q7);
      WAITV(8);  // R retired (new Q is the newest 8)
      unsigned accr = POLL_CHECK(r0, r1, r2, r3, r4, r5, r6, r7);
      if (__all((accr >> 16) == 0)) { use_r = 1; break; }
      POLL_ISSUE(r0, r1, r2, r3, r4, r5, r6, r7);
    }
    // NO drain of the losing set: it retires in the background during
    // compute (raw barriers below have no implicit vmcnt(0)).

    // ---- strip stamps, stage winning set into LDS ----
    if (use_r) {
      STAGE8(r0, r1, r2, r3, r4, r5, r6, r7);
    } else {
      STAGE8(q0, q1, q2, q3, q4, q5, q6, q7);
    }

    BARRIER_LDS();   // barrier A: h_lds fully staged (lgkm only)

    // ---- recurrent GEMM: A = h fragments from LDS, B = resident V ----
    f32x4 a0 = {0.f, 0.f, 0.f, 0.f}, a1 = {0.f, 0.f, 0.f, 0.f};
#pragma unroll
    for (int kt = 0; kt < 16; ++kt) {
      short8 af = *(const short8*)&h_lds[arow][kt * 32 + acol8];
      a0 = __builtin_amdgcn_mfma_f32_16x16x32_bf16(af, vfrag[0][kt], a0, 0, 0, 0);
      a1 = __builtin_amdgcn_mfma_f32_16x16x32_bf16(af, vfrag[1][kt], a1, 0, 0, 0);
    }

    *(short8*)&xbuf[xq][xb][xs * 8] = xv;
#pragma unroll
    for (int rr = 0; rr < 4; ++rr) {
      gbuf[wave][((lane >> 4) << 2) + rr][lane & 15] = a0[rr];
      gbuf[wave][((lane >> 4) << 2) + rr][16 + (lane & 15)] = a1[rr];
    }
    BARRIER_LDS();   // barrier B: gates ready (lgkm only)

    // ---- elementwise: 2 (b,d) elems per thread ----
    f32x2 vi = *(const f32x2*)&gbuf[0][br][dc];
    f32x2 vf = *(const f32x2*)&gbuf[1][br][dc];
    f32x2 vg = *(const f32x2*)&gbuf[2][br][dc];
    f32x2 vo = *(const f32x2*)&gbuf[3][br][dc];
    unsigned xi = *(const unsigned*)&xbuf[0][br][dc];
    unsigned xf = *(const unsigned*)&xbuf[1][br][dc];
    unsigned xg = *(const unsigned*)&xbuf[2][br][dc];
    unsigned xo = *(const unsigned*)&xbuf[3][br][dc];

    float i0 = sigm(vi[0] + bf2f((unsigned short)xi));
    float i1 = sigm(vi[1] + bf2f((unsigned short)(xi >> 16)));
    float f0v = sigm(vf[0] + bf2f((unsigned short)xf));
    float f1v = sigm(vf[1] + bf2f((unsigned short)(xf >> 16)));
    float g0 = tanh_f(vg[0] + bf2f((unsigned short)xg));
    float g1 = tanh_f(vg[1] + bf2f((unsigned short)(xg >> 16)));
    float o0 = sigm(vo[0] + bf2f((unsigned short)xo));
    float o1 = sigm(vo[1] + bf2f((unsigned short)(xo >> 16)));

    c0 = f0v * c0 + i0 * g0;
    c1 = f1v * c1 + i1 * g1;
    float h0 = o0 * tanh_f(c0);
    float h1 = o1 * tanh_f(c1);

    // ---- stamped h publish: fire-and-forget, device scope ----
    unsigned st = (unsigned)(t + 1) << 16;
    u32x2v sd;
    sd[0] = (unsigned)f2bf(h0) | st;
    sd[1] = (unsigned)f2bf(h1) | st;
    unsigned* hp = hstore0 + (((t + 1) & 1) ? 32768 : 0);
    asm volatile("global_store_dwordx2 %0, %1, off sc0 sc1"
                 :: "v"(hp), "v"(sd) : "memory");

    f32x2 hv = {h0, h1};
    *(f32x2*)(out + (size_t)batch * 262144 + (size_t)t * 512 + dglob) = hv;
    if (t == 511) {
      *(f32x2*)(out + 16777216 + batch * 512 + dglob) = hv;
      f32x2 cv = {c0, c1};
      *(f32x2*)(out + 16809984 + batch * 512 + dglob) = cv;
    }
    xv = xvn;

    // keep both poll sets' registers live to the end of the iteration so
    // in-flight returns of the losing set can only land in their own regs
    // (they are redefined by next iteration's POLL_ISSUE; vmcnt writeback
    // is in-order so old returns land before new ones).
    asm volatile("" :: "v"(q0), "v"(q1), "v"(q2), "v"(q3), "v"(q4), "v"(q5),
                 "v"(q6), "v"(q7), "v"(r0), "v"(r1), "v"(r2), "v"(r3),
                 "v"(r4), "v"(r5), "v"(r6), "v"(r7));
    // no end-of-step barrier: stamped-store -> poll is the inter-step sync.
  }
}

extern "C" void kernel_launch(void* const* d_in, const int* in_sizes, int n_in,
                              void* d_out, int out_size, void* d_ws, size_t ws_size,
                              hipStream_t stream) {
  const float* cas  = (const float*)d_in[0];
  const float* soc  = (const float*)d_in[1];
  const float* W    = (const float*)d_in[2];
  const float* U    = (const float*)d_in[3];
  const float* V    = (const float*)d_in[4];
  const float* bias = (const float*)d_in[5];
  float* out = (float*)d_out;
  char* ws = (char*)d_ws;

  unsigned short* xproj = (unsigned short*)(ws + 262144);  // 134,217,728 B
  unsigned short* Xcat  = xproj + (size_t)32768 * 2048;    // 67,108,864 B
  unsigned short* WUt   = Xcat + (size_t)32768 * 1024;     // 4,194,304 B
  unsigned short* Vt    = WUt + (size_t)2048 * 1024;       // 2,097,152 B
  // stamped h buffer reuses the head of Xcat (dead after k_gemm): 256KB
  unsigned* sh = (unsigned*)Xcat;

  k_convX<<<16384, 256, 0, stream>>>(cas, soc, Xcat);
  k_transpose<<<dim3(16, 32), 256, 0, stream>>>(W, U, 512, 1024, WUt);
  k_transpose<<<dim3(8, 32), 256, 0, stream>>>(V, V, 512, 512, Vt);
  k_gemm<<<dim3(16, 256), 256, 0, stream>>>(Xcat, WUt, bias, xproj);
  // zero stamps (epoch 0, h = 0) for both ping-pong slots
  hipMemsetAsync(sh, 0, 262144, stream);
  k_lstm<<<64, 256, 0, stream>>>(xproj, Vt, sh, out);
}

// Round 11
// 1373.945 us; speedup vs baseline: 1.4510x; 1.0999x over previous
//
#include <hip/hip_runtime.h>
#include <stdint.h>

// SharedLSTM: B=64, S=512, D=512.
//  out = concat(hidden_seq [64,512,512], h_T [64,512], c_T [64,512]) fp32.
//
// FINAL (round 11) = exact revert to round 5, the best harness-verified
// variant (k_lstm 1180us, total 1374us). Rounds 6-10 tested the remaining
// sync-chain levers and all regressed or were null:
//   r8  8wg-groups + in-reg elementwise: 1791us (bank conflicts, occupancy)
//   r9  2-set pipelined poll:            1335us (post-detect drain)
//   r10 r9 + raw lgkm barriers:          1316us (sets sample bunched ->
//                                        no quantization gain; bunching is
//                                        inherent to back-to-back issue)
// The recurrence is latency-bound (MfmaUtil 2%, HBM 5%): ~2 coherence-point
// round trips + ~700cy compute + straggler margin per step. This kernel is
// the verified floor of the stamped-data protocol family.
//
// Protocol (rounds 4-5, proven): h stored as stamped dwords
// (bf16 h | epoch<<16) with sc0 sc1, fire-and-forget — no fences, no flags,
// no barriers between workgroups. Consumers poll the DATA itself until
// every stamp == t (detect and load are one round trip; dword atomicity
// keeps h+stamp together). Ping-pong slots; flow control is emergent.
//
// ws layout:
//   [262144, +134217728)  x_proj bf16 [32768][2048]
//   then Xcat (67MB) — head reused after k_gemm as stamped-h sh (256KB,
//        memset between k_gemm and k_lstm), WUt (4MB), Vt (2MB)

typedef __attribute__((ext_vector_type(8))) short short8;
typedef __attribute__((ext_vector_type(4))) float f32x4;
typedef __attribute__((ext_vector_type(2))) float f32x2;
typedef __attribute__((ext_vector_type(4))) unsigned int u32x4v;
typedef __attribute__((ext_vector_type(2))) unsigned int u32x2v;

__device__ __forceinline__ unsigned short f2bf(float x) {
  union { float f; unsigned v; } c; c.f = x;
  unsigned r = (c.v + 0x7fffu + ((c.v >> 16) & 1u)) >> 16;  // RNE
  return (unsigned short)r;
}
__device__ __forceinline__ float bf2f(unsigned short u) {
  union { unsigned v; float f; } c; c.v = (unsigned)u << 16; return c.f;
}
__device__ __forceinline__ float sigm(float x) { return 1.f / (1.f + __expf(-x)); }
__device__ __forceinline__ float tanh_f(float x) { return 1.f - 2.f / (__expf(2.f * x) + 1.f); }

// ---------------- 1) concat + fp32->bf16 ----------------
__global__ __launch_bounds__(256) void k_convX(const float* __restrict__ cas,
                                               const float* __restrict__ soc,
                                               unsigned short* __restrict__ Xcat) {
  size_t i = ((size_t)blockIdx.x * 256 + threadIdx.x) * 8;  // elem in 32768*1024
  int r = (int)(i >> 10), k0 = (int)(i & 1023);
  const float* src = (k0 < 512) ? cas + (size_t)r * 512 + k0
                                : soc + (size_t)r * 512 + (k0 - 512);
  f32x4 a = *(const f32x4*)src;
  f32x4 b = *(const f32x4*)(src + 4);
  short8 o;
  o[0] = (short)f2bf(a[0]); o[1] = (short)f2bf(a[1]);
  o[2] = (short)f2bf(a[2]); o[3] = (short)f2bf(a[3]);
  o[4] = (short)f2bf(b[0]); o[5] = (short)f2bf(b[1]);
  o[6] = (short)f2bf(b[2]); o[7] = (short)f2bf(b[3]);
  *(short8*)(Xcat + i) = o;
}

// ---------------- 2) transpose + convert: Out[n][kk] = src(kk,n) -----------
__global__ __launch_bounds__(256) void k_transpose(const float* __restrict__ S0,
                                                   const float* __restrict__ S1,
                                                   int split, int Ktot,
                                                   unsigned short* __restrict__ Out) {
  __shared__ float tile[64][65];
  int tk = blockIdx.x, tn = blockIdx.y, tid = threadIdx.x;
#pragma unroll
  for (int i = 0; i < 16; ++i) {
    int idx = i * 256 + tid;
    int kr = idx >> 6, nc = idx & 63;
    int kk = tk * 64 + kr;
    const float* s = (kk < split) ? S0 + (size_t)kk * 2048 + tn * 64 + nc
                                  : S1 + (size_t)(kk - split) * 2048 + tn * 64 + nc;
    tile[kr][nc] = *s;
  }
  __syncthreads();
#pragma unroll
  for (int i = 0; i < 16; ++i) {
    int idx = i * 256 + tid;
    int nr = idx >> 6, kc = idx & 63;
    Out[(size_t)(tn * 64 + nr) * Ktot + tk * 64 + kc] = f2bf(tile[kc][nr]);
  }
}

// ---------------- 3) x_proj GEMM: 128x128 tile, BK=32, global_load_lds ------
__global__ __launch_bounds__(256) void k_gemm(const unsigned short* __restrict__ A,
                                              const unsigned short* __restrict__ Bt,
                                              const float* __restrict__ bias,
                                              unsigned short* __restrict__ xproj) {
  __shared__ __attribute__((aligned(16))) unsigned short At[128 * 32];
  __shared__ __attribute__((aligned(16))) unsigned short Bs[128 * 32];
  int tn0 = blockIdx.x * 128, tm0 = blockIdx.y * 128;
  int tid = threadIdx.x, wave = tid >> 6, lane = tid & 63;
  int wr = wave >> 1, wc = wave & 1;
  f32x4 acc[4][4] = {};

  for (int kt = 0; kt < 32; ++kt) {
    __syncthreads();
#pragma unroll
    for (int i = 0; i < 2; ++i) {
      int cb = i * 256 + wave * 64;
      int c = cb + lane;
      const unsigned short* ga = A + (size_t)(tm0 + (c >> 2)) * 1024 + kt * 32 + (c & 3) * 8;
      __builtin_amdgcn_global_load_lds((const __attribute__((address_space(1))) void*)ga,
                                       (__attribute__((address_space(3))) void*)(At + cb * 8),
                                       16, 0, 0);
      const unsigned short* gb = Bt + (size_t)(tn0 + (c >> 2)) * 1024 + kt * 32 + (c & 3) * 8;
      __builtin_amdgcn_global_load_lds((const __attribute__((address_space(1))) void*)gb,
                                       (__attribute__((address_space(3))) void*)(Bs + cb * 8),
                                       16, 0, 0);
    }
    __syncthreads();
    short8 af[4], bf[4];
#pragma unroll
    for (int m = 0; m < 4; ++m)
      af[m] = *(const short8*)(At + (wr * 64 + m * 16 + (lane & 15)) * 32 + (lane >> 4) * 8);
#pragma unroll
    for (int n = 0; n < 4; ++n)
      bf[n] = *(const short8*)(Bs + (wc * 64 + n * 16 + (lane & 15)) * 32 + (lane >> 4) * 8);
#pragma unroll
    for (int m = 0; m < 4; ++m)
#pragma unroll
      for (int n = 0; n < 4; ++n)
        acc[m][n] = __builtin_amdgcn_mfma_f32_16x16x32_bf16(af[m], bf[n], acc[m][n], 0, 0, 0);
  }

#pragma unroll
  for (int n = 0; n < 4; ++n) {
    int cg = tn0 + wc * 64 + n * 16 + (lane & 15);
    float bv = bias[cg];
#pragma unroll
    for (int m = 0; m < 4; ++m) {
#pragma unroll
      for (int rr = 0; rr < 4; ++rr) {
        int rg = tm0 + wr * 64 + m * 16 + ((lane >> 4) << 2) + rr;  // r = b*512+s
        int orow = ((rg & 511) << 6) | (rg >> 9);                   // s*64+b
        xproj[(size_t)orow * 2048 + cg] = f2bf(acc[m][n][rr] + bv);
      }
    }
  }
}

// ---------------- 4) persistent recurrence, epoch-stamped ----------------
// wg = (bg = blockIdx>>4, dg = blockIdx&15). Group = 16 wgs sharing bg.
// wave w = gate w; owns V^T rows [w*512+dg*32, +32) (vfrag[2][16]).
// sh dwords: sh[slot][batch][d] = (bf16 h) | (epoch<<16).
// Wave w polls the LINEAR slab rows [bg*16+4w, +4) x 512 d (8KB), fully
// coalesced (1KB contiguous per instruction), stages into LDS.
__global__ __launch_bounds__(256, 1) void k_lstm(const unsigned short* __restrict__ xproj,
                                                 const unsigned short* __restrict__ Vt,
                                                 unsigned* __restrict__ sh,
                                                 float* __restrict__ out) {
  __shared__ unsigned short h_lds[16][520];   // 1040B rows: 16B-aligned
  __shared__ float gbuf[4][16][32];
  __shared__ __attribute__((aligned(16))) unsigned short xbuf[4][16][32];

  int g = blockIdx.x;
  int bg = g >> 4, dg = g & 15;
  int tid = threadIdx.x, wave = tid >> 6, lane = tid & 63;

  // V fragments resident across the whole kernel: 2 tiles x 16 k-steps
  short8 vfrag[2][16];
#pragma unroll
  for (int hh = 0; hh < 2; ++hh)
#pragma unroll
    for (int kt = 0; kt < 16; ++kt) {
      int n = wave * 512 + dg * 32 + hh * 16 + (lane & 15);
      vfrag[hh][kt] = *(const short8*)(Vt + (size_t)n * 512 + kt * 32 + (lane >> 4) * 8);
    }

  float c0 = 0.f, c1 = 0.f;          // cell state in registers
  int br = tid >> 4;                 // batch row 0..15
  int dc = (tid & 15) * 2;           // d col (pair)
  int batch = bg * 16 + br;
  int dglob = dg * 32 + dc;

  int xb = tid >> 4, xq = (tid >> 2) & 3, xs = tid & 3;
  const unsigned short* xrow =
      xproj + (size_t)(bg * 16 + xb) * 2048 + xq * 512 + dg * 32 + xs * 8;

  int arow = lane & 15, acol8 = (lane >> 4) * 8;   // MFMA fragment row/col-base

  // linear poll base: wave w, lane l -> dword (bg*16)*512 + w*2048 + l*4
  const unsigned* pl0 = sh + (size_t)bg * 8192 + wave * 2048 + lane * 4;
  unsigned* hstore0 = sh + (size_t)batch * 512 + dglob;   // producer base

  short8 xv = *(const short8*)xrow;  // x_proj for t=0

  for (int t = 0; t < 512; ++t) {
    // ---- prefetch next step's x_proj FIRST: overlaps the poll RT, and is
    //      long done by barrier A
    short8 xvn = xv;
    if (t < 511) xvn = *(const short8*)(xrow + (size_t)(t + 1) * 131072);

    // ---- poll own linear slab of stamped h(t) until every stamp == t ----
    unsigned tsh = (unsigned)t << 16;
    const unsigned* pb = pl0 + ((t & 1) ? 32768 : 0);   // slot = 64*512 dwords
    const unsigned* pb4 = pb + 1024;                    // offset range > 4095B
    u32x4v q0, q1, q2, q3, q4, q5, q6, q7;
    while (true) {
      asm volatile(
          "global_load_dwordx4 %0, %8, off sc0 sc1\n\t"
          "global_load_dwordx4 %1, %8, off offset:1024 sc0 sc1\n\t"
          "global_load_dwordx4 %2, %8, off offset:2048 sc0 sc1\n\t"
          "global_load_dwordx4 %3, %8, off offset:3072 sc0 sc1\n\t"
          "global_load_dwordx4 %4, %9, off sc0 sc1\n\t"
          "global_load_dwordx4 %5, %9, off offset:1024 sc0 sc1\n\t"
          "global_load_dwordx4 %6, %9, off offset:2048 sc0 sc1\n\t"
          "global_load_dwordx4 %7, %9, off offset:3072 sc0 sc1\n\t"
          "s_waitcnt vmcnt(0)"
          : "=&v"(q0), "=&v"(q1), "=&v"(q2), "=&v"(q3),
            "=&v"(q4), "=&v"(q5), "=&v"(q6), "=&v"(q7)
          : "v"(pb), "v"(pb4)
          : "memory");
      unsigned acc =
          (q0[0] ^ tsh) | (q0[1] ^ tsh) | (q0[2] ^ tsh) | (q0[3] ^ tsh) |
          (q1[0] ^ tsh) | (q1[1] ^ tsh) | (q1[2] ^ tsh) | (q1[3] ^ tsh) |
          (q2[0] ^ tsh) | (q2[1] ^ tsh) | (q2[2] ^ tsh) | (q2[3] ^ tsh) |
          (q3[0] ^ tsh) | (q3[1] ^ tsh) | (q3[2] ^ tsh) | (q3[3] ^ tsh) |
          (q4[0] ^ tsh) | (q4[1] ^ tsh) | (q4[2] ^ tsh) | (q4[3] ^ tsh) |
          (q5[0] ^ tsh) | (q5[1] ^ tsh) | (q5[2] ^ tsh) | (q5[3] ^ tsh) |
          (q6[0] ^ tsh) | (q6[1] ^ tsh) | (q6[2] ^ tsh) | (q6[3] ^ tsh) |
          (q7[0] ^ tsh) | (q7[1] ^ tsh) | (q7[2] ^ tsh) | (q7[3] ^ tsh);
      if (__all((acc >> 16) == 0)) break;   // hi16 of every dword == t
    }

    // ---- strip stamps, stage into LDS ----
    // load j covers dwords w*2048 + j*256 + lane*4 .. +4
    //  -> row = w*4 + (j>>1), col = (j&1)*256 + lane*4
    {
      int r0 = wave * 4;
      int cA = lane * 4, cB = 256 + lane * 4;
      u32x2v p;
      p[0] = (q0[0] & 0xffffu) | (q0[1] << 16);
      p[1] = (q0[2] & 0xffffu) | (q0[3] << 16);
      *(u32x2v*)&h_lds[r0 + 0][cA] = p;
      p[0] = (q1[0] & 0xffffu) | (q1[1] << 16);
      p[1] = (q1[2] & 0xffffu) | (q1[3] << 16);
      *(u32x2v*)&h_lds[r0 + 0][cB] = p;
      p[0] = (q2[0] & 0xffffu) | (q2[1] << 16);
      p[1] = (q2[2] & 0xffffu) | (q2[3] << 16);
      *(u32x2v*)&h_lds[r0 + 1][cA] = p;
      p[0] = (q3[0] & 0xffffu) | (q3[1] << 16);
      p[1] = (q3[2] & 0xffffu) | (q3[3] << 16);
      *(u32x2v*)&h_lds[r0 + 1][cB] = p;
      p[0] = (q4[0] & 0xffffu) | (q4[1] << 16);
      p[1] = (q4[2] & 0xffffu) | (q4[3] << 16);
      *(u32x2v*)&h_lds[r0 + 2][cA] = p;
      p[0] = (q5[0] & 0xffffu) | (q5[1] << 16);
      p[1] = (q5[2] & 0xffffu) | (q5[3] << 16);
      *(u32x2v*)&h_lds[r0 + 2][cB] = p;
      p[0] = (q6[0] & 0xffffu) | (q6[1] << 16);
      p[1] = (q6[2] & 0xffffu) | (q6[3] << 16);
      *(u32x2v*)&h_lds[r0 + 3][cA] = p;
      p[0] = (q7[0] & 0xffffu) | (q7[1] << 16);
      p[1] = (q7[2] & 0xffffu) | (q7[3] << 16);
      *(u32x2v*)&h_lds[r0 + 3][cB] = p;
    }

    __syncthreads();   // barrier A: h_lds fully staged

    // ---- recurrent GEMM: A = h fragments from LDS, B = resident V ----
    f32x4 a0 = {0.f, 0.f, 0.f, 0.f}, a1 = {0.f, 0.f, 0.f, 0.f};
#pragma unroll
    for (int kt = 0; kt < 16; ++kt) {
      short8 af = *(const short8*)&h_lds[arow][kt * 32 + acol8];
      a0 = __builtin_amdgcn_mfma_f32_16x16x32_bf16(af, vfrag[0][kt], a0, 0, 0, 0);
      a1 = __builtin_amdgcn_mfma_f32_16x16x32_bf16(af, vfrag[1][kt], a1, 0, 0, 0);
    }

    *(short8*)&xbuf[xq][xb][xs * 8] = xv;
#pragma unroll
    for (int rr = 0; rr < 4; ++rr) {
      gbuf[wave][((lane >> 4) << 2) + rr][lane & 15] = a0[rr];
      gbuf[wave][((lane >> 4) << 2) + rr][16 + (lane & 15)] = a1[rr];
    }
    __syncthreads();   // barrier B: gates ready

    // ---- elementwise: 2 (b,d) elems per thread ----
    f32x2 vi = *(const f32x2*)&gbuf[0][br][dc];
    f32x2 vf = *(const f32x2*)&gbuf[1][br][dc];
    f32x2 vg = *(const f32x2*)&gbuf[2][br][dc];
    f32x2 vo = *(const f32x2*)&gbuf[3][br][dc];
    unsigned xi = *(const unsigned*)&xbuf[0][br][dc];
    unsigned xf = *(const unsigned*)&xbuf[1][br][dc];
    unsigned xg = *(const unsigned*)&xbuf[2][br][dc];
    unsigned xo = *(const unsigned*)&xbuf[3][br][dc];

    float i0 = sigm(vi[0] + bf2f((unsigned short)xi));
    float i1 = sigm(vi[1] + bf2f((unsigned short)(xi >> 16)));
    float f0v = sigm(vf[0] + bf2f((unsigned short)xf));
    float f1v = sigm(vf[1] + bf2f((unsigned short)(xf >> 16)));
    float g0 = tanh_f(vg[0] + bf2f((unsigned short)xg));
    float g1 = tanh_f(vg[1] + bf2f((unsigned short)(xg >> 16)));
    float o0 = sigm(vo[0] + bf2f((unsigned short)xo));
    float o1 = sigm(vo[1] + bf2f((unsigned short)(xo >> 16)));

    c0 = f0v * c0 + i0 * g0;
    c1 = f1v * c1 + i1 * g1;
    float h0 = o0 * tanh_f(c0);
    float h1 = o1 * tanh_f(c1);

    // ---- stamped h publish: fire-and-forget, device scope ----
    unsigned st = (unsigned)(t + 1) << 16;
    u32x2v sd;
    sd[0] = (unsigned)f2bf(h0) | st;
    sd[1] = (unsigned)f2bf(h1) | st;
    unsigned* hp = hstore0 + (((t + 1) & 1) ? 32768 : 0);
    asm volatile("global_store_dwordx2 %0, %1, off sc0 sc1"
                 :: "v"(hp), "v"(sd) : "memory");

    f32x2 hv = {h0, h1};
    *(f32x2*)(out + (size_t)batch * 262144 + (size_t)t * 512 + dglob) = hv;
    if (t == 511) {
      *(f32x2*)(out + 16777216 + batch * 512 + dglob) = hv;
      f32x2 cv = {c0, c1};
      *(f32x2*)(out + 16809984 + batch * 512 + dglob) = cv;
    }
    xv = xvn;
    // no end-of-step barrier: stamped-store -> poll is the inter-step sync.
  }
}

extern "C" void kernel_launch(void* const* d_in, const int* in_sizes, int n_in,
                              void* d_out, int out_size, void* d_ws, size_t ws_size,
                              hipStream_t stream) {
  const float* cas  = (const float*)d_in[0];
  const float* soc  = (const float*)d_in[1];
  const float* W    = (const float*)d_in[2];
  const float* U    = (const float*)d_in[3];
  const float* V    = (const float*)d_in[4];
  const float* bias = (const float*)d_in[5];
  float* out = (float*)d_out;
  char* ws = (char*)d_ws;

  unsigned short* xproj = (unsigned short*)(ws + 262144);  // 134,217,728 B
  unsigned short* Xcat  = xproj + (size_t)32768 * 2048;    // 67,108,864 B
  unsigned short* WUt   = Xcat + (size_t)32768 * 1024;     // 4,194,304 B
  unsigned short* Vt    = WUt + (size_t)2048 * 1024;       // 2,097,152 B
  // stamped h buffer reuses the head of Xcat (dead after k_gemm): 256KB
  unsigned* sh = (unsigned*)Xcat;

  k_convX<<<16384, 256, 0, stream>>>(cas, soc, Xcat);
  k_transpose<<<dim3(16, 32), 256, 0, stream>>>(W, U, 512, 1024, WUt);
  k_transpose<<<dim3(8, 32), 256, 0, stream>>>(V, V, 512, 512, Vt);
  k_gemm<<<dim3(16, 256), 256, 0, stream>>>(Xcat, WUt, bias, xproj);
  // zero stamps (epoch 0, h = 0) for both ping-pong slots
  hipMemsetAsync(sh, 0, 262144, stream);
  k_lstm<<<64, 256, 0, stream>>>(xproj, Vt, sh, out);
}